// Round 1
// baseline (440.226 us; speedup 1.0000x reference)
//
#include <hip/hip_runtime.h>
#include <hip/hip_bf16.h>

#define S_  2048
#define B_  2
#define D_  1024
#define H_  16
#define F_  4096
#define HD_ 64
#define NT_ (S_*B_)   // 4096 tokens

typedef __attribute__((ext_vector_type(8))) short short8;
typedef __attribute__((ext_vector_type(4))) short short4v;
typedef __attribute__((ext_vector_type(4))) float f32x4;

#define MFMA16x16x32(a,b,c) __builtin_amdgcn_mfma_f32_16x16x32_bf16((a),(b),(c),0,0,0)

__device__ __forceinline__ short f2b(float f) {
  union { float f; unsigned u; } x; x.f = f;
  unsigned r = x.u + 0x7FFFu + ((x.u >> 16) & 1u);
  return (short)(r >> 16);
}

// ---------------- elementwise fp32 -> bf16 ----------------
__global__ __launch_bounds__(256) void to_bf16_k(const float* __restrict__ in,
                                                 short* __restrict__ out) {
  int i = (blockIdx.x * 256 + threadIdx.x) * 8;
  float4 a = *(const float4*)(in + i);
  float4 b = *(const float4*)(in + i + 4);
  short8 o;
  o[0] = f2b(a.x); o[1] = f2b(a.y); o[2] = f2b(a.z); o[3] = f2b(a.w);
  o[4] = f2b(b.x); o[5] = f2b(b.y); o[6] = f2b(b.z); o[7] = f2b(b.w);
  *(short8*)(out + i) = o;
}

// ---------------- W[K,N] fp32 -> Wt[(n+colbase)][k] bf16 ----------------
__global__ __launch_bounds__(256) void transpose_to_bf16(const float* __restrict__ W,
                                                         short* __restrict__ Wt,
                                                         int K, int N, int colbase, int outK) {
  __shared__ short t[32][33];
  int tx = threadIdx.x & 31, ty = threadIdx.x >> 5;  // ty 0..7
  int kbase = blockIdx.y * 32, nbase = blockIdx.x * 32;
#pragma unroll
  for (int yy = 0; yy < 4; ++yy) {
    int kk = ty + yy * 8;
    t[kk][tx] = f2b(W[(size_t)(kbase + kk) * N + nbase + tx]);
  }
  __syncthreads();
#pragma unroll
  for (int yy = 0; yy < 4; ++yy) {
    int nn = ty + yy * 8;
    Wt[(size_t)(nbase + nn + colbase) * outK + kbase + tx] = t[tx][nn];
  }
}

// ---------------- GEMM: C[M,N] = A[M,K](bf16) @ Bt[N,K]^T(bf16) + epilogue ----------------
// MODE 0: QKV  (bias q/k/v, q scaled 0.125, writes q[b,h,s,d], k[b,h,s,d], v[b,h,d,s] bf16)
// MODE 1: out = acc + bias + resid   (fp32)
// MODE 2: out = relu(acc + bias)     (bf16)
template<int MODE>
__global__ __launch_bounds__(256, 2) void gemm_bt(
    const short* __restrict__ A, const short* __restrict__ Bt,
    int M, int N, int K,
    const float* __restrict__ bias0, const float* __restrict__ bias1,
    const float* __restrict__ bias2,
    const float* __restrict__ resid, float* __restrict__ outf,
    short* __restrict__ outq, short* __restrict__ outk, short* __restrict__ outv) {
  __shared__ short As[128][40];
  __shared__ short Bs[128][40];
  int tid = threadIdx.x;
  int lane = tid & 63, w = tid >> 6;
  int g = lane >> 4, r = lane & 15;
  int wm = w >> 1, wn = w & 1;
  int row0 = blockIdx.y * 128, col0 = blockIdx.x * 128;

  f32x4 acc[4][4];
#pragma unroll
  for (int m = 0; m < 4; ++m)
#pragma unroll
    for (int n = 0; n < 4; ++n) acc[m][n] = (f32x4){0.f, 0.f, 0.f, 0.f};

  for (int kt = 0; kt < K; kt += 32) {
    __syncthreads();
#pragma unroll
    for (int p = 0; p < 2; ++p) {
      int idx = tid + p * 256;
      int row = idx >> 2, c = (idx & 3) * 8;
      *(short8*)&As[row][c] = *(const short8*)(A  + (size_t)(row0 + row) * K + kt + c);
      *(short8*)&Bs[row][c] = *(const short8*)(Bt + (size_t)(col0 + row) * K + kt + c);
    }
    __syncthreads();
    short8 af[4], bfr[4];
#pragma unroll
    for (int m = 0; m < 4; ++m) af[m]  = *(const short8*)&As[wm * 64 + m * 16 + r][g * 8];
#pragma unroll
    for (int n = 0; n < 4; ++n) bfr[n] = *(const short8*)&Bs[wn * 64 + n * 16 + r][g * 8];
#pragma unroll
    for (int m = 0; m < 4; ++m)
#pragma unroll
      for (int n = 0; n < 4; ++n)
        acc[m][n] = MFMA16x16x32(af[m], bfr[n], acc[m][n]);
  }

  int rb = row0 + wm * 64, cb = col0 + wn * 64;
#pragma unroll
  for (int m = 0; m < 4; ++m) {
#pragma unroll
    for (int n = 0; n < 4; ++n) {
#pragma unroll
      for (int j = 0; j < 4; ++j) {
        int row = rb + m * 16 + g * 4 + j;
        int col = cb + n * 16 + r;
        float v = acc[m][n][j];
        if (MODE == 0) {
          int s = row >> 1, b = row & 1;
          if (col < 1024) {
            float q = (v + bias0[col]) * 0.125f;
            int h = col >> 6, hd = col & 63;
            outq[((size_t)(b * H_ + h) * S_ + s) * HD_ + hd] = f2b(q);
          } else if (col < 2048) {
            int c2 = col - 1024;
            float kk = v + bias1[c2];
            int h = c2 >> 6, hd = c2 & 63;
            outk[((size_t)(b * H_ + h) * S_ + s) * HD_ + hd] = f2b(kk);
          } else {
            int c2 = col - 2048;
            float vv = v + bias2[c2];
            int h = c2 >> 6, hd = c2 & 63;
            outv[((size_t)(b * H_ + h) * HD_ + hd) * S_ + s] = f2b(vv);
          }
        } else if (MODE == 1) {
          size_t o = (size_t)row * N + col;
          outf[o] = v + bias0[col] + resid[o];
        } else {
          size_t o = (size_t)row * N + col;
          float t = v + bias0[col];
          outq[o] = f2b(t > 0.f ? t : 0.f);
        }
      }
    }
  }
}

// ---------------- flash attention ----------------
// Q,K: [b*H+h][s][d] bf16 (Q pre-scaled by 0.125), Vt: [b*H+h][d][s] bf16
// ctx out: token-major [s*B+b][h*64+hd] bf16
__global__ __launch_bounds__(256, 2) void flash_attn(const short* __restrict__ Q,
                                                     const short* __restrict__ Kb,
                                                     const short* __restrict__ Vt,
                                                     short* __restrict__ ctx) {
  __shared__ short P[4][32][40];
  int lane = threadIdx.x & 63, w = threadIdx.x >> 6;
  int g = lane >> 4, r = lane & 15;
  int bh = blockIdx.y, qb = blockIdx.x;
  const short* qp = Q  + (size_t)bh * S_ * HD_;
  const short* kp = Kb + (size_t)bh * S_ * HD_;
  const short* vp = Vt + (size_t)bh * HD_ * S_;
  int q0 = qb * 128 + w * 32;

  short8 qf[2][2];
#pragma unroll
  for (int m = 0; m < 2; ++m)
#pragma unroll
    for (int kk = 0; kk < 2; ++kk)
      qf[m][kk] = *(const short8*)(qp + (size_t)(q0 + m * 16 + r) * HD_ + kk * 32 + g * 8);

  f32x4 acc[2][4];
  float mi[2][4], li[2][4];
#pragma unroll
  for (int m = 0; m < 2; ++m)
#pragma unroll
    for (int j = 0; j < 4; ++j) { mi[m][j] = -1e30f; li[m][j] = 0.f; }
#pragma unroll
  for (int m = 0; m < 2; ++m)
#pragma unroll
    for (int nd = 0; nd < 4; ++nd) acc[m][nd] = (f32x4){0.f, 0.f, 0.f, 0.f};

  for (int kv0 = 0; kv0 < S_; kv0 += 32) {
    short8 kf[2][2];
#pragma unroll
    for (int n = 0; n < 2; ++n)
#pragma unroll
      for (int kk = 0; kk < 2; ++kk)
        kf[n][kk] = *(const short8*)(kp + (size_t)(kv0 + n * 16 + r) * HD_ + kk * 32 + g * 8);

    f32x4 sf[2][2];
#pragma unroll
    for (int m = 0; m < 2; ++m)
#pragma unroll
      for (int n = 0; n < 2; ++n) {
        f32x4 t = (f32x4){0.f, 0.f, 0.f, 0.f};
#pragma unroll
        for (int kk = 0; kk < 2; ++kk) t = MFMA16x16x32(qf[m][kk], kf[n][kk], t);
        sf[m][n] = t;
      }

    // online softmax per q-row (row = g*4+j within fragment m)
#pragma unroll
    for (int m = 0; m < 2; ++m) {
#pragma unroll
      for (int j = 0; j < 4; ++j) {
        float pm = fmaxf(sf[m][0][j], sf[m][1][j]);
        pm = fmaxf(pm, __shfl_xor(pm, 1, 64));
        pm = fmaxf(pm, __shfl_xor(pm, 2, 64));
        pm = fmaxf(pm, __shfl_xor(pm, 4, 64));
        pm = fmaxf(pm, __shfl_xor(pm, 8, 64));
        float mn = fmaxf(mi[m][j], pm);
        float sc = __expf(mi[m][j] - mn);
        mi[m][j] = mn;
        float rs = 0.f;
#pragma unroll
        for (int n = 0; n < 2; ++n) {
          float p0 = __expf(sf[m][n][j] - mn);
          sf[m][n][j] = p0;
          rs += p0;
        }
        rs += __shfl_xor(rs, 1, 64);
        rs += __shfl_xor(rs, 2, 64);
        rs += __shfl_xor(rs, 4, 64);
        rs += __shfl_xor(rs, 8, 64);
        li[m][j] = li[m][j] * sc + rs;
#pragma unroll
        for (int nd = 0; nd < 4; ++nd) acc[m][nd][j] *= sc;
      }
    }

    // P (C-layout) -> LDS -> A-layout bf16 fragments
#pragma unroll
    for (int m = 0; m < 2; ++m)
#pragma unroll
      for (int n = 0; n < 2; ++n)
#pragma unroll
        for (int j = 0; j < 4; ++j)
          P[w][m * 16 + g * 4 + j][n * 16 + r] = f2b(sf[m][n][j]);

    short8 pf[2];
#pragma unroll
    for (int m = 0; m < 2; ++m) pf[m] = *(const short8*)&P[w][m * 16 + r][g * 8];

    short8 vf[4];
#pragma unroll
    for (int nd = 0; nd < 4; ++nd)
      vf[nd] = *(const short8*)(vp + (size_t)(nd * 16 + r) * S_ + kv0 + g * 8);

#pragma unroll
    for (int m = 0; m < 2; ++m)
#pragma unroll
      for (int nd = 0; nd < 4; ++nd)
        acc[m][nd] = MFMA16x16x32(pf[m], vf[nd], acc[m][nd]);
  }

  int b = bh >> 4, h = bh & 15;
#pragma unroll
  for (int m = 0; m < 2; ++m) {
#pragma unroll
    for (int j = 0; j < 4; ++j) {
      float inv = 1.0f / li[m][j];
      int srow = q0 + m * 16 + g * 4 + j;
      int token = srow * B_ + b;
#pragma unroll
      for (int nd = 0; nd < 4; ++nd) {
        int col = h * 64 + nd * 16 + r;
        ctx[(size_t)token * D_ + col] = f2b(acc[m][nd][j] * inv);
      }
    }
  }
}

// ---------------- layernorm (row = 1024 fp32), optional bf16 copy ----------------
__global__ __launch_bounds__(256) void layernorm_k(const float* __restrict__ y,
                                                   const float* __restrict__ gm,
                                                   const float* __restrict__ bt,
                                                   float* __restrict__ of,
                                                   short* __restrict__ ob, int writeb) {
  __shared__ float r1[4], r2[4];
  int row = blockIdx.x, tid = threadIdx.x;
  const float* yr = y + (size_t)row * D_;
  float4 v = *(const float4*)(yr + tid * 4);
  float s1 = v.x + v.y + v.z + v.w;
  float s2 = v.x * v.x + v.y * v.y + v.z * v.z + v.w * v.w;
#pragma unroll
  for (int off = 32; off > 0; off >>= 1) {
    s1 += __shfl_xor(s1, off, 64);
    s2 += __shfl_xor(s2, off, 64);
  }
  int wid = tid >> 6;
  if ((tid & 63) == 0) { r1[wid] = s1; r2[wid] = s2; }
  __syncthreads();
  s1 = r1[0] + r1[1] + r1[2] + r1[3];
  s2 = r2[0] + r2[1] + r2[2] + r2[3];
  float mean = s1 * (1.0f / D_);
  float var = s2 * (1.0f / D_) - mean * mean;
  float rstd = rsqrtf(var + 1e-5f);
  float4 gv = *(const float4*)(gm + tid * 4);
  float4 bv = *(const float4*)(bt + tid * 4);
  float o0 = (v.x - mean) * rstd * gv.x + bv.x;
  float o1 = (v.y - mean) * rstd * gv.y + bv.y;
  float o2 = (v.z - mean) * rstd * gv.z + bv.z;
  float o3 = (v.w - mean) * rstd * gv.w + bv.w;
  float4* op = (float4*)(of + (size_t)row * D_ + tid * 4);
  *op = make_float4(o0, o1, o2, o3);
  if (writeb) {
    short4v o;
    o[0] = f2b(o0); o[1] = f2b(o1); o[2] = f2b(o2); o[3] = f2b(o3);
    *(short4v*)(ob + (size_t)row * D_ + tid * 4) = o;
  }
}

extern "C" void kernel_launch(void* const* d_in, const int* in_sizes, int n_in,
                              void* d_out, int out_size, void* d_ws, size_t ws_size,
                              hipStream_t stream) {
  const float* src = (const float*)d_in[0];
  const float* Wq  = (const float*)d_in[1];
  const float* bq  = (const float*)d_in[2];
  const float* Wk  = (const float*)d_in[3];
  const float* bk  = (const float*)d_in[4];
  const float* Wv  = (const float*)d_in[5];
  const float* bv  = (const float*)d_in[6];
  const float* Wo  = (const float*)d_in[7];
  const float* bo  = (const float*)d_in[8];
  const float* g1  = (const float*)d_in[9];
  const float* be1 = (const float*)d_in[10];
  const float* W1  = (const float*)d_in[11];
  const float* bf1 = (const float*)d_in[12];
  const float* W2  = (const float*)d_in[13];
  const float* bf2 = (const float*)d_in[14];
  const float* g2  = (const float*)d_in[15];
  const float* be2 = (const float*)d_in[16];
  float* out = (float*)d_out;
  char* ws = (char*)d_ws;

  // workspace layout (bytes), lifetime-overlapped; total 104 MiB
  short* Wqkv_t = (short*)(ws + 0);          // 6 MiB  [3072][1024]
  short* Wo_t   = (short*)(ws + 6291456);    // 2 MiB  [1024][1024]
  short* W1_t   = (short*)(ws + 8388608);    // 8 MiB  [4096][1024]
  short* W2_t   = (short*)(ws + 16777216);   // 8 MiB  [1024][4096]
  short* xb     = (short*)(ws + 25165824);   // 8 MiB  src bf16
  short* ctx    = (short*)(ws + 33554432);   // 8 MiB
  float* res1   = (float*)(ws + 41943040);   // 16 MiB
  short* hid    = (short*)(ws + 25165824);   // 32 MiB, overlays xb|ctx|res1 (all dead)
  short* qb_    = (short*)(ws + 58720256);   // 8 MiB
  short* kb_    = (short*)(ws + 67108864);   // 8 MiB
  float* res2   = (float*)(ws + 58720256);   // 16 MiB, overlays q|k (dead)
  short* vb_    = (short*)(ws + 75497472);   // 8 MiB
  float* x1f    = (float*)(ws + 83886080);   // 16 MiB
  short* x1b    = (short*)(ws + 100663296);  // 8 MiB   (end: 109051904)

  to_bf16_k<<<2048, 256, 0, stream>>>(src, xb);

  transpose_to_bf16<<<dim3(32, 32),  256, 0, stream>>>(Wq, Wqkv_t, 1024, 1024, 0,    1024);
  transpose_to_bf16<<<dim3(32, 32),  256, 0, stream>>>(Wk, Wqkv_t, 1024, 1024, 1024, 1024);
  transpose_to_bf16<<<dim3(32, 32),  256, 0, stream>>>(Wv, Wqkv_t, 1024, 1024, 2048, 1024);
  transpose_to_bf16<<<dim3(32, 32),  256, 0, stream>>>(Wo, Wo_t,   1024, 1024, 0,    1024);
  transpose_to_bf16<<<dim3(128, 32), 256, 0, stream>>>(W1, W1_t,   1024, 4096, 0,    1024);
  transpose_to_bf16<<<dim3(32, 128), 256, 0, stream>>>(W2, W2_t,   4096, 1024, 0,    4096);

  // QKV projection (M=4096, N=3072, K=1024)
  gemm_bt<0><<<dim3(24, 32), 256, 0, stream>>>(xb, Wqkv_t, NT_, 3072, 1024,
                                               bq, bk, bv, nullptr, nullptr, qb_, kb_, vb_);
  // attention
  flash_attn<<<dim3(16, 32), 256, 0, stream>>>(qb_, kb_, vb_, ctx);
  // out-proj + residual(src) -> res1
  gemm_bt<1><<<dim3(8, 32), 256, 0, stream>>>(ctx, Wo_t, NT_, 1024, 1024,
                                              bo, nullptr, nullptr, src, res1,
                                              nullptr, nullptr, nullptr);
  // LN1 -> x1f (fp32) + x1b (bf16)
  layernorm_k<<<NT_, 256, 0, stream>>>(res1, g1, be1, x1f, x1b, 1);
  // FFN1 + ReLU -> hid (bf16, M=4096, N=4096, K=1024)
  gemm_bt<2><<<dim3(32, 32), 256, 0, stream>>>(x1b, W1_t, NT_, 4096, 1024,
                                               bf1, nullptr, nullptr, nullptr, nullptr,
                                               hid, nullptr, nullptr);
  // FFN2 + residual(x1f) -> res2 (M=4096, N=1024, K=4096)
  gemm_bt<1><<<dim3(8, 32), 256, 0, stream>>>(hid, W2_t, NT_, 1024, 4096,
                                              bf2, nullptr, nullptr, x1f, res2,
                                              nullptr, nullptr, nullptr);
  // LN2 -> out
  layernorm_k<<<NT_, 256, 0, stream>>>(res2, g2, be2, out, nullptr, 0);
}